// Round 5
// baseline (142.788 us; speedup 1.0000x reference)
//
#include <hip/hip_runtime.h>
#include <hip/hip_bf16.h>

using short8 = __attribute__((ext_vector_type(8))) short;
using f32x4  = __attribute__((ext_vector_type(4))) float;

#define N_TOK   8192
#define DIM     128
#define JS      32                 // j-splits
#define JCH     (N_TOK / JS)       // 256 j per wave
#define NT      (JCH / 16)         // 16 j-tiles per wave
#define EXP10F  22026.465794806718f
#define SCALE   3.79828262f        // sqrt(10/ln2): dot of scaled vecs = 10*sim/ln2 -> exp2 arg

// ---------------- Kernel A: row-normalize, scale, cast to bf16, pack keys ----------------
__global__ void norm_cast_kernel(const float* __restrict__ feats,
                                 const int* __restrict__ did,
                                 const int* __restrict__ iid,
                                 __hip_bfloat16* __restrict__ xb,
                                 int* __restrict__ keys) {
  const int wid  = threadIdx.x >> 6;
  const int lane = threadIdx.x & 63;
  const int row  = blockIdx.x * 4 + wid;   // one wave per row
  const float2 v = *reinterpret_cast<const float2*>(feats + row * DIM + lane * 2);
  float ss = v.x * v.x + v.y * v.y;
  #pragma unroll
  for (int m = 1; m < 64; m <<= 1) ss += __shfl_xor(ss, m, 64);
  const float scale = SCALE / fmaxf(sqrtf(ss), 1e-12f);
  __hip_bfloat162 pair;
  pair.x = __float2bfloat16(v.x * scale);
  pair.y = __float2bfloat16(v.y * scale);
  *reinterpret_cast<__hip_bfloat162*>(xb + row * DIM + lane * 2) = pair;
  if (lane == 0) keys[row] = (did[row] << 5) | iid[row];   // did in [0,4), iid in [0,32)
}

// ---------------- Kernel B: fused sim -> exp -> masked row sums (LDS-free) ----------------
// Each wave independently owns 64 i-rows x 256 j-cols. No barriers, no LDS.
// B fragments loaded straight from global (xb is 2MB -> fully L2-resident per XCD).
// Branchless epilogue; exp2 argument produced directly by the MFMA (inputs pre-scaled).
__launch_bounds__(256)
__global__ void sim_kernel(const __hip_bfloat16* __restrict__ xb,
                           const int* __restrict__ keys,
                           float* __restrict__ pos_sum,
                           float* __restrict__ neg_sum) {
  const int tid  = threadIdx.x;
  const int lane = tid & 63, wid = tid >> 6;
  const int w    = blockIdx.x * 4 + wid;
  const int iw   = w >> 5;          // 128 i-waves (64 rows each)
  const int js   = w & (JS - 1);
  const int l15  = lane & 15, l4 = lane >> 4;
  const int i0   = iw * 64;

  // A fragments: rows i0 + m*16 + l15, k = ks*32 + l4*8 (8 contiguous bf16)
  short8 a[4][4];
  #pragma unroll
  for (int m = 0; m < 4; ++m)
    #pragma unroll
    for (int ks = 0; ks < 4; ++ks)
      a[m][ks] = *reinterpret_cast<const short8*>(xb + (size_t)(i0 + m * 16 + l15) * DIM + ks * 32 + l4 * 8);

  // Per-lane i-row keys (C/D layout: row = l4*4 + r within each 16-row fragment)
  int ki[16];
  #pragma unroll
  for (int m = 0; m < 4; ++m)
    #pragma unroll
    for (int r = 0; r < 4; ++r)
      ki[m * 4 + r] = keys[i0 + m * 16 + l4 * 4 + r];

  float pos_p[16], neg_p[16];
  #pragma unroll
  for (int t = 0; t < 16; ++t) { pos_p[t] = 0.0f; neg_p[t] = 0.0f; }

  #pragma unroll 2
  for (int t = 0; t < NT; ++t) {
    const int j0 = js * JCH + t * 16;
    const int jg = j0 + l15;          // this lane's column index
    const int kj = keys[jg];
    short8 b[4];
    #pragma unroll
    for (int ks = 0; ks < 4; ++ks)
      b[ks] = *reinterpret_cast<const short8*>(xb + (size_t)jg * DIM + ks * 32 + l4 * 8);

    #pragma unroll
    for (int m = 0; m < 4; ++m) {
      f32x4 acc = {0.0f, 0.0f, 0.0f, 0.0f};
      #pragma unroll
      for (int ks = 0; ks < 4; ++ks)
        acc = __builtin_amdgcn_mfma_f32_16x16x32_bf16(a[m][ks], b[ks], acc, 0, 0, 0);
      #pragma unroll
      for (int r = 0; r < 4; ++r) {
        const int ig   = i0 + m * 16 + l4 * 4 + r;
        const int k_i  = ki[m * 4 + r];
        const float e  = __builtin_amdgcn_exp2f(acc[r]);   // = exp(10*sim)
        const bool same = (k_i == kj);
        const bool diag = (ig == jg);
        const bool dds  = ((k_i ^ kj) >> 5) != 0;  // different dataset
        float nw = dds ? (e + e) : e;              // neg weight*e for non-matching keys
        nw = same ? 0.0f : nw;
        nw = diag ? EXP10F : nw;                   // diagonal: sim==1 exactly, weight 1
        const float pw = (same && !diag) ? e : 0.0f;
        neg_p[m * 4 + r] += nw;
        pos_p[m * 4 + r] += pw;
      }
    }
  }

  // reduce each per-row partial across the 16 lanes (low 4 bits) holding that row
  #pragma unroll
  for (int t = 0; t < 16; ++t) {
    float p = pos_p[t], q = neg_p[t];
    #pragma unroll
    for (int m = 1; m < 16; m <<= 1) {
      p += __shfl_xor(p, m, 64);
      q += __shfl_xor(q, m, 64);
    }
    if (l15 == 0) {
      const int ig = i0 + (t >> 2) * 16 + l4 * 4 + (t & 3);
      atomicAdd(&pos_sum[ig], p);
      atomicAdd(&neg_sum[ig], q);
    }
  }
}

// ---------------- Kernel C: per-row loss + masked mean ----------------
__global__ void loss_kernel(const float* __restrict__ pos_sum,
                            const float* __restrict__ neg_sum,
                            float* __restrict__ out) {
  const int tid = threadIdx.x;
  const int lane = tid & 63, wid = tid >> 6;
  float sm = 0.0f, sa = 0.0f;
  int cnt = 0;
  #pragma unroll
  for (int it = 0; it < N_TOK / 1024; ++it) {
    const int i = tid + it * 1024;
    const float p = pos_sum[i], q = neg_sum[i];
    const float loss = -logf(p / (p + q + 1e-8f));
    sa += loss;
    if (p > 0.0f) { sm += loss; cnt++; }
  }
  #pragma unroll
  for (int m = 1; m < 64; m <<= 1) {
    sm += __shfl_xor(sm, m, 64);
    sa += __shfl_xor(sa, m, 64);
    cnt += __shfl_xor(cnt, m, 64);
  }
  __shared__ float r_sm[16], r_sa[16];
  __shared__ int r_c[16];
  if (lane == 0) { r_sm[wid] = sm; r_sa[wid] = sa; r_c[wid] = cnt; }
  __syncthreads();
  if (tid == 0) {
    float tsm = 0.0f, tsa = 0.0f;
    int tc = 0;
    for (int w2 = 0; w2 < 16; ++w2) { tsm += r_sm[w2]; tsa += r_sa[w2]; tc += r_c[w2]; }
    out[0] = (tc > 0) ? (tsm / (float)tc) : (tsa / (float)N_TOK);
  }
}

extern "C" void kernel_launch(void* const* d_in, const int* in_sizes, int n_in,
                              void* d_out, int out_size, void* d_ws, size_t ws_size,
                              hipStream_t stream) {
  const float* feats = (const float*)d_in[0];
  const int* did = (const int*)d_in[1];
  const int* iid = (const int*)d_in[2];
  float* out = (float*)d_out;

  char* ws = (char*)d_ws;
  __hip_bfloat16* xb = (__hip_bfloat16*)ws;                    // 2 MB
  int* keys   = (int*)(ws + (size_t)N_TOK * DIM * 2);          // 32 KB
  float* pos  = (float*)((char*)keys + N_TOK * 4);             // 32 KB
  float* neg  = pos + N_TOK;                                   // 32 KB

  (void)hipMemsetAsync(pos, 0, (size_t)N_TOK * 2 * sizeof(float), stream);

  norm_cast_kernel<<<N_TOK / 4, 256, 0, stream>>>(feats, did, iid, xb, keys);
  sim_kernel<<<(N_TOK / 64) * JS / 4, 256, 0, stream>>>(xb, keys, pos, neg);
  loss_kernel<<<1, 1024, 0, stream>>>(pos, neg, out);
}

// Round 9
// 141.265 us; speedup vs baseline: 1.0108x; 1.0108x over previous
//
#include <hip/hip_runtime.h>
#include <hip/hip_bf16.h>

using short8 = __attribute__((ext_vector_type(8))) short;
using f32x4  = __attribute__((ext_vector_type(4))) float;

#define N_TOK   8192
#define DIM     128
#define JS      32                 // j-splits
#define JCH     (N_TOK / JS)       // 256 j per wave
#define NT      (JCH / 16)         // 16 j-tiles per wave
#define ROWS    32                 // i-rows per wave
#define EXP10F  22026.465794806718f
#define SCALE   3.79828262f        // sqrt(10/ln2): dot of scaled vecs = 10*sim/ln2 -> exp2 arg

// ---------------- Kernel A: row-normalize, scale, cast to bf16, pack keys, zero accum ----------------
__global__ void norm_cast_kernel(const float* __restrict__ feats,
                                 const int* __restrict__ did,
                                 const int* __restrict__ iid,
                                 __hip_bfloat16* __restrict__ xb,
                                 int* __restrict__ keys,
                                 float* __restrict__ accum /* pos||neg, 16384 floats */) {
  const int wid  = threadIdx.x >> 6;
  const int lane = threadIdx.x & 63;
  const int row  = blockIdx.x * 4 + wid;   // one wave per row
  // zero pos/neg accumulators (replaces a memset dispatch): 8 floats per block
  if (threadIdx.x < 8) accum[blockIdx.x * 8 + threadIdx.x] = 0.0f;
  const float2 v = *reinterpret_cast<const float2*>(feats + row * DIM + lane * 2);
  float ss = v.x * v.x + v.y * v.y;
  #pragma unroll
  for (int m = 1; m < 64; m <<= 1) ss += __shfl_xor(ss, m, 64);
  const float scale = SCALE / fmaxf(sqrtf(ss), 1e-12f);
  __hip_bfloat162 pair;
  pair.x = __float2bfloat16(v.x * scale);
  pair.y = __float2bfloat16(v.y * scale);
  *reinterpret_cast<__hip_bfloat162*>(xb + row * DIM + lane * 2) = pair;
  if (lane == 0) keys[row] = (did[row] << 5) | iid[row];   // did in [0,4), iid in [0,32)
}

// ---------------- Kernel B: fused sim -> exp -> masked row sums ----------------
// Wave owns 32 i-rows x 256 j-cols. No LDS, no barriers. B double-buffered in regs.
// Epilogue accumulates N = sum (dds?2:1)*e over ALL j and P = sum_{same key} e;
// per-row neg contribution = N - P (linear), pos = P. Diagonal element is zeroed
// in-kernel (only the tiles that contain it check) and exp(10) is re-added in loss.
__launch_bounds__(256, 4)
__global__ void sim_kernel(const __hip_bfloat16* __restrict__ xb,
                           const int* __restrict__ keys,
                           float* __restrict__ pos_sum,
                           float* __restrict__ neg_sum) {
  const int tid  = threadIdx.x;
  const int lane = tid & 63, wid = tid >> 6;
  const int w    = blockIdx.x * 4 + wid;     // 8192 waves
  const int iw   = w >> 5;                   // 256 i-waves (32 rows each)
  const int js   = w & (JS - 1);
  const int l15  = lane & 15, l4 = lane >> 4;
  const int i0   = iw * ROWS;
  const int jbase = js * JCH;

  // A fragments: rows i0 + m*16 + l15, k = ks*32 + l4*8
  short8 a[2][4];
  #pragma unroll
  for (int m = 0; m < 2; ++m)
    #pragma unroll
    for (int ks = 0; ks < 4; ++ks)
      a[m][ks] = *reinterpret_cast<const short8*>(xb + (size_t)(i0 + m * 16 + l15) * DIM + ks * 32 + l4 * 8);

  // Per-lane i-row keys (C/D layout: row = l4*4 + r)
  int ki[8];
  #pragma unroll
  for (int m = 0; m < 2; ++m)
    #pragma unroll
    for (int r = 0; r < 4; ++r)
      ki[m * 4 + r] = keys[i0 + m * 16 + l4 * 4 + r];

  float aN[8], aP[8];
  #pragma unroll
  for (int t = 0; t < 8; ++t) { aN[t] = 0.0f; aP[t] = 0.0f; }

  short8 b0[4], b1[4];
  int kj0, kj1;

  auto loadB = [&](short8 (&b)[4], int& kj, int t) {
    const int jg = jbase + t * 16 + l15;
    kj = keys[jg];
    const __hip_bfloat16* bp = xb + (size_t)jg * DIM + l4 * 8;
    #pragma unroll
    for (int ks = 0; ks < 4; ++ks)
      b[ks] = *reinterpret_cast<const short8*>(bp + ks * 32);
  };

  auto compute = [&](const short8 (&b)[4], int kj, int t) {
    const int j0 = jbase + t * 16;
    const bool hasdiag = ((unsigned)(j0 - i0) < (unsigned)ROWS);  // wave-uniform
    #pragma unroll
    for (int m = 0; m < 2; ++m) {
      f32x4 acc = {0.0f, 0.0f, 0.0f, 0.0f};
      #pragma unroll
      for (int ks = 0; ks < 4; ++ks)
        acc = __builtin_amdgcn_mfma_f32_16x16x32_bf16(a[m][ks], b[ks], acc, 0, 0, 0);
      #pragma unroll
      for (int r = 0; r < 4; ++r) {
        const int idx = m * 4 + r;
        const int x   = ki[idx] ^ kj;          // 0 => same key; >31 => different dataset
        const float e = __builtin_amdgcn_exp2f(acc[r]);   // = exp(10*sim)
        float nw = (x > 31) ? (e + e) : e;
        float pe = (x == 0) ? e : 0.0f;
        if (hasdiag) {
          const int ig = i0 + m * 16 + l4 * 4 + r;
          const int jg = j0 + l15;
          if (ig == jg) { nw = 0.0f; pe = 0.0f; }   // drop diagonal entirely
        }
        aN[idx] += nw;
        aP[idx] += pe;
      }
    }
  };

  loadB(b0, kj0, 0);
  loadB(b1, kj1, 1);
  for (int t = 0; t < NT - 2; t += 2) {
    compute(b0, kj0, t);
    loadB(b0, kj0, t + 2);
    compute(b1, kj1, t + 1);
    loadB(b1, kj1, t + 3);
  }
  compute(b0, kj0, NT - 2);
  compute(b1, kj1, NT - 1);

  // reduce across the 16 lanes (low 4 bits) holding each row; neg partial = N - P
  #pragma unroll
  for (int t = 0; t < 8; ++t) {
    float p = aP[t];
    float q = aN[t] - aP[t];
    #pragma unroll
    for (int m = 1; m < 16; m <<= 1) {
      p += __shfl_xor(p, m, 64);
      q += __shfl_xor(q, m, 64);
    }
    if (l15 == 0) {
      const int ig = i0 + (t >> 2) * 16 + l4 * 4 + (t & 3);
      atomicAdd(&pos_sum[ig], p);
      atomicAdd(&neg_sum[ig], q);
    }
  }
}

// ---------------- Kernel C: per-row loss + masked mean ----------------
// neg_sum is missing the diagonal term: add exp(10) (exact) here.
__global__ void loss_kernel(const float* __restrict__ pos_sum,
                            const float* __restrict__ neg_sum,
                            float* __restrict__ out) {
  const int tid = threadIdx.x;
  const int lane = tid & 63, wid = tid >> 6;
  float sm = 0.0f, sa = 0.0f;
  int cnt = 0;
  #pragma unroll
  for (int it = 0; it < 2; ++it) {
    const int base = (it * 1024 + tid) * 4;
    const float4 p4 = *reinterpret_cast<const float4*>(pos_sum + base);
    const float4 q4 = *reinterpret_cast<const float4*>(neg_sum + base);
    #pragma unroll
    for (int k = 0; k < 4; ++k) {
      const float p = (k == 0) ? p4.x : (k == 1) ? p4.y : (k == 2) ? p4.z : p4.w;
      const float qr = (k == 0) ? q4.x : (k == 1) ? q4.y : (k == 2) ? q4.z : q4.w;
      const float q = qr + EXP10F;
      const float loss = -logf(p / (p + q + 1e-8f));
      sa += loss;
      if (p > 0.0f) { sm += loss; cnt++; }
    }
  }
  #pragma unroll
  for (int m = 1; m < 64; m <<= 1) {
    sm += __shfl_xor(sm, m, 64);
    sa += __shfl_xor(sa, m, 64);
    cnt += __shfl_xor(cnt, m, 64);
  }
  __shared__ float r_sm[16], r_sa[16];
  __shared__ int r_c[16];
  if (lane == 0) { r_sm[wid] = sm; r_sa[wid] = sa; r_c[wid] = cnt; }
  __syncthreads();
  if (tid == 0) {
    float tsm = 0.0f, tsa = 0.0f;
    int tc = 0;
    for (int w2 = 0; w2 < 16; ++w2) { tsm += r_sm[w2]; tsa += r_sa[w2]; tc += r_c[w2]; }
    out[0] = (tc > 0) ? (tsm / (float)tc) : (tsa / (float)N_TOK);
  }
}

extern "C" void kernel_launch(void* const* d_in, const int* in_sizes, int n_in,
                              void* d_out, int out_size, void* d_ws, size_t ws_size,
                              hipStream_t stream) {
  const float* feats = (const float*)d_in[0];
  const int* did = (const int*)d_in[1];
  const int* iid = (const int*)d_in[2];
  float* out = (float*)d_out;

  char* ws = (char*)d_ws;
  __hip_bfloat16* xb = (__hip_bfloat16*)ws;                    // 2 MB
  int* keys   = (int*)(ws + (size_t)N_TOK * DIM * 2);          // 32 KB
  float* pos  = (float*)((char*)keys + N_TOK * 4);             // 32 KB
  float* neg  = pos + N_TOK;                                   // 32 KB

  norm_cast_kernel<<<N_TOK / 4, 256, 0, stream>>>(feats, did, iid, xb, keys, pos);
  sim_kernel<<<(N_TOK / ROWS) * JS / 4, 256, 0, stream>>>(xb, keys, pos, neg);
  loss_kernel<<<1, 1024, 0, stream>>>(pos, neg, out);
}